// Round 17
// baseline (32.196 us; speedup 1.0000x reference)
//
#include <hip/hip_runtime.h>
#include <hip/hip_bf16.h>
#include <hip/hip_fp16.h>
#include <math.h>

#define HDIM 150

typedef __fp16   f16x8  __attribute__((ext_vector_type(8)));   // matches builtin 'h'
typedef __fp16   f16x2  __attribute__((ext_vector_type(2)));
typedef float    f32x4  __attribute__((ext_vector_type(4)));

__device__ __forceinline__ unsigned int pk16(float a, float b) {
    f16x2 p = __builtin_amdgcn_cvt_pkrtz(a, b);
    unsigned int w; __builtin_memcpy(&w, &p, 4);
    return w;
}

__device__ __forceinline__ f16x2 swap_halves(f16x2 v) {
    unsigned int u; __builtin_memcpy(&u, &v, 4);
    u = __builtin_amdgcn_alignbit(u, u, 16);
    f16x2 r; __builtin_memcpy(&r, &u, 4);
    return r;
}

// ---------------------------------------------------------------------------
// fully unrolled Batcher odd-even mergesort, n = 16 (f16x2: lows and highs
// sorted INDEPENDENTLY via v_pk_min/max_f16)
// ---------------------------------------------------------------------------
template <typename T>
__device__ __forceinline__ void cswapT(T& a, T& b) {
    T lo = __builtin_elementwise_min(a, b);
    T hi = __builtin_elementwise_max(a, b);
    a = lo; b = hi;
}

template <typename T>
__device__ __forceinline__ void sort16t(T v[16]) {
#pragma unroll
    for (int pp = 1; pp < 16; pp <<= 1) {
#pragma unroll
        for (int k = pp; k >= 1; k >>= 1) {
#pragma unroll
            for (int j = k & (pp - 1); j + k < 16; j += 2 * k) {
#pragma unroll
                for (int i = 0; i < k; ++i) {
                    if ((i + j) / (2 * pp) == (i + j + k) / (2 * pp))
                        cswapT(v[i + j], v[i + j + k]);
                }
            }
        }
    }
}

// ---------------------------------------------------------------------------
// k_all R25: R24 + paired h-write diet + early x pre-issue.
//  * h-write: tiles 2z and 2z+1 hit the SAME site (mm = m, m+16). Hold the
//    even tile's 4 f32 sums in regs; at the odd tile pack
//    cvt_pkrtz(s_even, s_odd) -> relu -> 4 ds_write_b32 per tile-PAIR.
//    Replaces 8 scalar ds_write_u16 per pair (-32 LDS instrs/thread, zero
//    extra pack ops). sH becomes u32 [site][p (stride 20 u32 = 80 B)][m],
//    value = f16x2 (read m, read m+16). The median halver identity needs
//    only SOME partition into two sorted 16-subsets, so pairing (k, k+16)
//    is as valid as (2k, 2k+1) -- agg code unchanged except the base ptr.
//  * x tiles 0/1 pre-issued BEFORE the blob build: both paths now go to
//    registers (R15's LDS-DMA vmcnt ordering hazard doesn't apply); the
//    first gather's ~500cyc hides under the ~1Kcyc blob prologue.
// Kept from R20-R24: f16 MFMA everywhere, direct-global blob build, packed
// relu/sort, fdot2 stats, transposed 20-tile head staging, 5 barriers.
//
// LDS overlay (35840 B, 4 blocks/CU):
//   [0,20480)      phase B: sH  32 x (8 x 20 u32) = 640B/site
//                  phase D: head frag tiles, 20 x 1KB  [after bar4]
//   [20480,35840)  phase A: MLP frag blob, 15 tiles x 1KB (pulled at barB)
//                  phase C: sAgg (5632) @20480 | sB3 @26112 | sW4 @26752 |
//                           sPart @27392   (overlays dead blob tiles)
// ---------------------------------------------------------------------------
#define FB_OFF     20480
#define AGG_OFF    20480
#define B3_OFF     26112
#define W4_OFF     26752
#define PART_OFF   27392
#define SMEM_TOTAL 35840

__global__ __launch_bounds__(256, 4) void k_all(
    const float* __restrict__ x, const int* __restrict__ kmer,
    const int* __restrict__ indices, const float* __restrict__ emb,
    const float* __restrict__ W1, const float* __restrict__ b1,
    const float* __restrict__ W2, const float* __restrict__ b2,
    const float* __restrict__ W3, const float* __restrict__ b3,
    const float* __restrict__ W4, const float* __restrict__ b4,
    float* __restrict__ out, int Gtot)
{
    __shared__ __align__(16) char smem[SMEM_TOTAL];

    const int tid  = threadIdx.x;
    const int lane = tid & 63;
    const int wv   = tid >> 6;
    const int m    = lane & 15;
    const int q    = lane >> 4;

    const int gblk  = blockIdx.x * 32;           // first site of this block
    const int rbase = gblk * 32;                 // first flat read-slot

    // ---- read indices (everything depends on them) ----
    int rg[4];
    {
        const int lim = Gtot * 32 - 1;
#pragma unroll
        for (int g = 0; g < 4; ++g) {
            int fl = rbase + wv * 256 + g * 64 + lane;
            rg[g] = indices[fl > lim ? lim : fl];
        }
    }

    const char* xg = (const char*)x;

    // ---- 2-tile-deep register pipeline for the x gather; tiles 0/1 issued
    //      NOW so their latency hides under the blob prologue ----
    f32x4 xa[2][2];
    auto issueTile = [&](int t) {
        int rr = __shfl(rg[t >> 2], ((t & 3) << 4) + m);
        if (q < 2) {
            const f32x4* src = (const f32x4*)(xg + (size_t)rr * 64 + (size_t)q * 32);
            xa[t & 1][0] = src[0];
            xa[t & 1][1] = src[1];
        }
    };
    issueTile(0);
    issueTile(1);

    // ---- emb chain (dependent gather; also hides under the prologue) ----
    unsigned int egp[4];                         // packed f16 (ex,ey)
    {
        int kk[4];
#pragma unroll
        for (int g = 0; g < 4; ++g) kk[g] = kmer[rg[g]];
        const float2* emb2 = (const float2*)emb;
#pragma unroll
        for (int g = 0; g < 4; ++g) {
            float2 e = emb2[kk[g]];
            egp[g] = pk16(e.x, e.y);
        }
    }

    // ---- phase A: build f16 fragment blob in LDS, weights read straight
    //      from global (L2-resident) ----
    uint4* fb4w = (uint4*)(smem + FB_OFF);
    {
        const int c  = tid >> 6;                 // tile chunk 0..3
        const int tn = (c < 3) ? 4 : 3;          // tiles 0..14
        for (int tt = 0; tt < tn; ++tt) {
            const int tile = c * 4 + tt;
            unsigned int w[4];
#pragma unroll
            for (int dw = 0; dw < 4; ++dw) {
                const int d = tile * 4 + dw;
                float v0 = 0.f, v1 = 0.f;
                if (d < 40) {
                    int n = d >> 2, j0 = (d & 3) * 2;
                    // permuted hidden rows for the register relay:
                    //   tile 2kt   row(4q+r) = hidden 32kt+8q+r
                    //   tile 2kt+1 row(4q+r) = hidden 32kt+8q+4+r
                    int hid = 32 * (n >> 1) + 8 * (m >> 2) + 4 * (n & 1) + (m & 3);
                    if (hid < HDIM) {
                        int k0 = q * 8 + j0, k1 = k0 + 1;
                        v0 = (k0 < 18) ? W1[k0 * HDIM + hid] : (k0 == 18 ? b1[hid] : 0.f);
                        v1 = (k1 < 18) ? W1[k1 * HDIM + hid] : (k1 == 18 ? b1[hid] : 0.f);
                    }
                } else {
                    int kt = (d - 40) >> 2, j0 = ((d - 40) & 3) * 2;
                    int k0 = kt * 32 + q * 8 + j0, k1 = k0 + 1;
                    if (m < 8) {
                        v0 = (k0 < HDIM) ? W2[k0 * 8 + m]
                                         : (k0 == HDIM ? b2[m] : 0.f);   // b2 row
                        v1 = (k1 < HDIM) ? W2[k1 * 8 + m]
                                         : (k1 == HDIM ? b2[m] : 0.f);
                    }
                }
                w[dw] = pk16(v0, v1);
            }
            fb4w[tile * 64 + lane] = make_uint4(w[0], w[1], w[2], w[3]);
        }
    }
    __syncthreads();                             // barA (blob built)

    // ---- ALL 15 fragment tiles pulled into registers (read LDS once) ----
    uint4 B16[15];
    const uint4* fb4 = (const uint4*)fb4w;
#pragma unroll
    for (int i = 0; i < 15; ++i) B16[i] = fb4[i * 64 + lane];
    const f16x8* frv = (const f16x8*)B16;        // frv[0..9]=L1, frv[10..14]=L2
    __syncthreads();                             // barB: blob region reusable

    unsigned int* sH32 = (unsigned int*)smem;    // [site][p*20][m] f16x2 words
    const f32x4 zero = {0.f, 0.f, 0.f, 0.f};
    const f16x2 z2 = {};

    float se0 = 0.f, se1 = 0.f, se2 = 0.f, se3 = 0.f;   // even-tile sums

#pragma unroll
    for (int t = 0; t < 16; ++t) {
        unsigned int ew = __shfl((int)egp[t >> 2], ((t & 3) << 4) + m);

        // input B-fragment: B[k = q*8+j][n = read m]
        f16x8 bin;
#pragma unroll
        for (int j = 0; j < 8; ++j) bin[j] = (__fp16)0.f;
        if (q < 2) {
            f32x4 u0 = xa[t & 1][0];
            f32x4 u1 = xa[t & 1][1];
            f16x2 p0 = __builtin_amdgcn_cvt_pkrtz(u0[0], u0[1]);
            f16x2 p1 = __builtin_amdgcn_cvt_pkrtz(u0[2], u0[3]);
            f16x2 p2 = __builtin_amdgcn_cvt_pkrtz(u1[0], u1[1]);
            f16x2 p3 = __builtin_amdgcn_cvt_pkrtz(u1[2], u1[3]);
            bin[0] = p0[0]; bin[1] = p0[1]; bin[2] = p1[0]; bin[3] = p1[1];
            bin[4] = p2[0]; bin[5] = p2[1]; bin[6] = p3[0]; bin[7] = p3[1];
        } else if (q == 2) {
            f16x2 ep; __builtin_memcpy(&ep, &ew, 4);
            bin[0] = ep[0]; bin[1] = ep[1];
            bin[2] = (__fp16)1.0f;   // bias-1 input at k==18
        }

        // refill this ring slot with tile t+2 (loads overlap the MFMAs)
        if (t < 14) issueTile(t + 2);

        // layer1 (reg frags) -> packed relu -> layer2 (reg frags)
        f32x4 c2a = zero, c2b = zero;
#pragma unroll
        for (int kt = 0; kt < 5; ++kt) {
            f32x4 ca = __builtin_amdgcn_mfma_f32_16x16x32_f16(frv[2 * kt],     bin, zero, 0, 0, 0);
            f32x4 cb = __builtin_amdgcn_mfma_f32_16x16x32_f16(frv[2 * kt + 1], bin, zero, 0, 0, 0);
            f16x2 h01 = __builtin_elementwise_max(__builtin_amdgcn_cvt_pkrtz(ca[0], ca[1]), z2);
            f16x2 h23 = __builtin_elementwise_max(__builtin_amdgcn_cvt_pkrtz(ca[2], ca[3]), z2);
            f16x2 h45 = __builtin_elementwise_max(__builtin_amdgcn_cvt_pkrtz(cb[0], cb[1]), z2);
            f16x2 h67 = __builtin_elementwise_max(__builtin_amdgcn_cvt_pkrtz(cb[2], cb[3]), z2);
            f16x8 bh;
            bh[0] = h01[0]; bh[1] = h01[1]; bh[2] = h23[0]; bh[3] = h23[1];
            bh[4] = h45[0]; bh[5] = h45[1]; bh[6] = h67[0]; bh[7] = h67[1];
            if (kt == 4 && q == 2) bh[6] = (__fp16)1.0f;   // bias row k==150
            if (kt & 1) c2b = __builtin_amdgcn_mfma_f32_16x16x32_f16(frv[10 + kt], bh, c2b, 0, 0, 0);
            else        c2a = __builtin_amdgcn_mfma_f32_16x16x32_f16(frv[10 + kt], bh, c2a, 0, 0, 0);
        }

        // h: even tile -> hold sums in regs; odd tile -> pack (even,odd)
        // per p and write 4 x ds_write_b32 (tiles 2z/2z+1 share a site)
        if (q < 2) {
            float s0 = c2a[0] + c2b[0], s1 = c2a[1] + c2b[1];
            float s2 = c2a[2] + c2b[2], s3 = c2a[3] + c2b[3];
            if (!(t & 1)) {
                se0 = s0; se1 = s1; se2 = s2; se3 = s3;
            } else {
                int site = wv * 8 + (t >> 1);
                f16x2 w0 = __builtin_elementwise_max(__builtin_amdgcn_cvt_pkrtz(se0, s0), z2);
                f16x2 w1 = __builtin_elementwise_max(__builtin_amdgcn_cvt_pkrtz(se1, s1), z2);
                f16x2 w2 = __builtin_elementwise_max(__builtin_amdgcn_cvt_pkrtz(se2, s2), z2);
                f16x2 w3 = __builtin_elementwise_max(__builtin_amdgcn_cvt_pkrtz(se3, s3), z2);
                unsigned int u0, u1, u2, u3;
                __builtin_memcpy(&u0, &w0, 4);
                __builtin_memcpy(&u1, &w1, 4);
                __builtin_memcpy(&u2, &w2, 4);
                __builtin_memcpy(&u3, &w3, 4);
                unsigned int* hb = sH32 + site * 160 + m;
                hb[(q * 4 + 0) * 20] = u0;
                hb[(q * 4 + 1) * 20] = u1;
                hb[(q * 4 + 2) * 20] = u2;
                hb[(q * 4 + 3) * 20] = u3;
            }
        }
    }
    // NO barrier: agg reads only this wave's own sites (same-wave RAW via
    // lgkmcnt); sAgg region was freed at barB.

    float* sAgg = (float*)(smem + AGG_OFF);
    float* sPart= (float*)(smem + PART_OFF);

    // ---- T14 async-stage, TRANSPOSED, ALL 20 TILES: thread t owns head-frag
    //      dword (tile j=0..19, lane t>>2, dw t&3); load its W3 pair now
    //      (L2-hot; agg hides latency), pack immediately (20 dwords).
    const int fl_ = tid >> 2, fdw = tid & 3;     // frag (lane, dword) owned
    const int fm = fl_ & 15, fq = fl_ >> 4;
    unsigned int hw[20];
#pragma unroll
    for (int j = 0; j < 20; ++j) {
        int jt = j >> 1, kc = j & 1;
        int row = jt * 16 + fm;
        int k0  = kc * 32 + fq * 8 + fdw * 2;
        float v0 = (k0     < 40 && row < HDIM) ? W3[k0 * HDIM + row]       : 0.f;
        float v1 = (k0 + 1 < 40 && row < HDIM) ? W3[(k0 + 1) * HDIM + row] : 0.f;
        hw[j] = pk16(v0, v1);
    }
    float b3r = 0.f, w4r = 0.f;
    if (tid < 160) {
        b3r = (tid < HDIM) ? b3[tid] : 0.f;
        w4r = (tid < HDIM) ? W4[tid] : 0.f;
    }

    // ---- aggregation: packed f16 stats + packed sort + halver merge ----
    // v[k] = (read k, read k+16): a valid partition for the median identity
    const int sg = tid >> 3, p = tid & 7;
    {
        const uint4* hp4 = (const uint4*)(sH32 + sg * 160 + p * 20);
        uint4 rr4[4];
#pragma unroll
        for (int c = 0; c < 4; ++c) rr4[c] = hp4[c];
        f16x2 v[16];
        __builtin_memcpy(v, rr4, 64);

        // sum / sumsq via v_dot2_f32_f16 (exact f16 mul, f32 accumulate)
        float sum = 0.f, sumsq = 0.f;
        const f16x2 ones = {(__fp16)1.0f, (__fp16)1.0f};
#pragma unroll
        for (int k = 0; k < 16; ++k) {
            sum   = __builtin_amdgcn_fdot2(v[k], ones, sum, false);
            sumsq = __builtin_amdgcn_fdot2(v[k], v[k], sumsq, false);
        }

        // packed sort: lows = sorted reads 0..15, highs = sorted reads 16..31
        sort16t(v);

        float mn = fminf((float)v[0][0],  (float)v[0][1]);
        float mx = fmaxf((float)v[15][0], (float)v[15][1]);

        // lower median of 32 = max_i min(a[i], b[15-i]); highs mirror lows
        f16x2 medv = __builtin_elementwise_min(v[0], swap_halves(v[15]));
#pragma unroll
        for (int i = 1; i < 16; ++i)
            medv = __builtin_elementwise_max(
                medv, __builtin_elementwise_min(v[i], swap_halves(v[15 - i])));
        float med = (float)medv[0];

        float mean = sum * (1.f / 32.f);
        float var  = fmaxf((sumsq - 32.f * mean * mean) * (1.f / 31.f), 0.f);
        sAgg[sg * 44 + 0 * 8 + p] = mean;
        sAgg[sg * 44 + 1 * 8 + p] = var;
        sAgg[sg * 44 + 2 * 8 + p] = mn;
        sAgg[sg * 44 + 3 * 8 + p] = med;
        sAgg[sg * 44 + 4 * 8 + p] = mx;
    }
    __syncthreads();   // bar4: all agg done; sH dead -> head frag tiles there

    // ---- phase D: write head fragment tiles (f16) + b3/W4 ----
    unsigned int* hfT = (unsigned int*)smem;     // 20 tiles x 256 dwords
#pragma unroll
    for (int j = 0; j < 20; ++j)
        hfT[j * 256 + tid] = hw[j];
    float* sB3 = (float*)(smem + B3_OFF);
    float* sW4 = (float*)(smem + W4_OFF);
    if (tid < 160) { sB3[tid] = b3r; sW4[tid] = w4r; }
    __syncthreads();   // bar5

    // ---- lanes pull their 10 head-fragment uint4s ----
    const int jthalf = wv >> 1, sh = wv & 1;
    uint4 HF[10];
    {
        const uint4* hfv = (const uint4*)hfT;
#pragma unroll
        for (int i = 0; i < 10; ++i) {
            int jt = jthalf * 5 + (i >> 1), kc = i & 1;
            HF[i] = hfv[(jt * 2 + kc) * 64 + lane];
        }
    }
    const f16x8* hf = (const f16x8*)HF;

    // ---- head MLP via f16 MFMA: Z[j][site] = W3^T @ AGG, wave=(jthalf,sh) --
    // B-frag: lane(m,q) holds AGG[k = kc*32+q*8+j][site sh*16+m], split hi/lo
    const int site = sh * 16 + m;
    const float* ar = sAgg + site * 44;
    f16x8 bh0, bl0, bh1, bl1;
    {
        float4 a0 = *(const float4*)(ar + q * 8);
        float4 a1 = *(const float4*)(ar + q * 8 + 4);
        float va[8] = {a0.x, a0.y, a0.z, a0.w, a1.x, a1.y, a1.z, a1.w};
#pragma unroll
        for (int j = 0; j < 8; ++j) {
            __fp16 hi = (__fp16)va[j];
            bh0[j] = hi;
            bl0[j] = (__fp16)(va[j] - (float)hi);
        }
    }
    if (q == 0) {       // kc=1 covers k = 32..39 (stat 4); other q are zero
        float4 a0 = *(const float4*)(ar + 32);
        float4 a1 = *(const float4*)(ar + 36);
        float va[8] = {a0.x, a0.y, a0.z, a0.w, a1.x, a1.y, a1.z, a1.w};
#pragma unroll
        for (int j = 0; j < 8; ++j) {
            __fp16 hi = (__fp16)va[j];
            bh1[j] = hi;
            bl1[j] = (__fp16)(va[j] - (float)hi);
        }
    } else {
#pragma unroll
        for (int j = 0; j < 8; ++j) { bh1[j] = (__fp16)0.f; bl1[j] = (__fp16)0.f; }
    }

    const float4* b3v = (const float4*)sB3;
    const float4* w4v = (const float4*)sW4;
    float sacc = 0.f;
#pragma unroll
    for (int jj = 0; jj < 5; ++jj) {
        int jt = jthalf * 5 + jj;
        float4 bi = b3v[jt * 4 + q];             // rows jt*16+q*4 .. +3
        f32x4 acc = {bi.x, bi.y, bi.z, bi.w};
        acc = __builtin_amdgcn_mfma_f32_16x16x32_f16(hf[jj * 2 + 0], bh0, acc, 0, 0, 0);
        acc = __builtin_amdgcn_mfma_f32_16x16x32_f16(hf[jj * 2 + 0], bl0, acc, 0, 0, 0);
        acc = __builtin_amdgcn_mfma_f32_16x16x32_f16(hf[jj * 2 + 1], bh1, acc, 0, 0, 0);
        acc = __builtin_amdgcn_mfma_f32_16x16x32_f16(hf[jj * 2 + 1], bl1, acc, 0, 0, 0);
        float4 w4q = w4v[jt * 4 + q];
        sacc = fmaf(fmaxf(acc[0], 0.f), w4q.x, sacc);
        sacc = fmaf(fmaxf(acc[1], 0.f), w4q.y, sacc);
        sacc = fmaf(fmaxf(acc[2], 0.f), w4q.z, sacc);
        sacc = fmaf(fmaxf(acc[3], 0.f), w4q.w, sacc);
    }
    // reduce over the 4 q row-groups (j within tile), then across jthalf waves
    sacc += __shfl_xor(sacc, 16);
    sacc += __shfl_xor(sacc, 32);
    if (jthalf == 1 && lane < 16) sPart[sh * 16 + lane] = sacc;
    __syncthreads();   // bar6
    if (jthalf == 0 && lane < 16) {
        int s2 = sh * 16 + lane;
        float zf = sacc + sPart[s2] + b4[0];
        if (gblk + s2 < Gtot) out[gblk + s2] = 1.f / (1.f + expf(-zf));
    }
}

// ---------------------------------------------------------------------------
extern "C" void kernel_launch(void* const* d_in, const int* in_sizes, int n_in,
                              void* d_out, int out_size, void* d_ws, size_t ws_size,
                              hipStream_t stream) {
    const float* x       = (const float*)d_in[0];
    const int*   kmer    = (const int*)  d_in[1];
    const int*   indices = (const int*)  d_in[2];
    const float* emb     = (const float*)d_in[3];
    const float* W1      = (const float*)d_in[4];
    const float* b1      = (const float*)d_in[5];
    const float* W2      = (const float*)d_in[6];
    const float* b2      = (const float*)d_in[7];
    const float* W3      = (const float*)d_in[8];
    const float* b3      = (const float*)d_in[9];
    const float* W4      = (const float*)d_in[10];
    const float* b4      = (const float*)d_in[11];

    float* out = (float*)d_out;
    const int G = out_size;

    const int grid = (G + 31) / 32;              // 32 sites / block
    k_all<<<grid, 256, 0, stream>>>(x, kmer, indices, emb,
                                    W1, b1, W2, b2, W3, b3, W4, b4,
                                    out, G);
}

// Round 18
// 31.843 us; speedup vs baseline: 1.0111x; 1.0111x over previous
//
#include <hip/hip_runtime.h>
#include <hip/hip_bf16.h>
#include <hip/hip_fp16.h>
#include <math.h>

#define HDIM 150

typedef __fp16   f16x8  __attribute__((ext_vector_type(8)));   // matches builtin 'h'
typedef __fp16   f16x2  __attribute__((ext_vector_type(2)));
typedef float    f32x4  __attribute__((ext_vector_type(4)));

__device__ __forceinline__ unsigned int pk16(float a, float b) {
    f16x2 p = __builtin_amdgcn_cvt_pkrtz(a, b);
    unsigned int w; __builtin_memcpy(&w, &p, 4);
    return w;
}

__device__ __forceinline__ f16x2 swap_halves(f16x2 v) {
    unsigned int u; __builtin_memcpy(&u, &v, 4);
    u = __builtin_amdgcn_alignbit(u, u, 16);
    f16x2 r; __builtin_memcpy(&r, &u, 4);
    return r;
}

// ---------------------------------------------------------------------------
// fully unrolled Batcher odd-even mergesort, n = 16 (f16x2: lows and highs
// sorted INDEPENDENTLY via v_pk_min/max_f16)
// ---------------------------------------------------------------------------
template <typename T>
__device__ __forceinline__ void cswapT(T& a, T& b) {
    T lo = __builtin_elementwise_min(a, b);
    T hi = __builtin_elementwise_max(a, b);
    a = lo; b = hi;
}

template <typename T>
__device__ __forceinline__ void sort16t(T v[16]) {
#pragma unroll
    for (int pp = 1; pp < 16; pp <<= 1) {
#pragma unroll
        for (int k = pp; k >= 1; k >>= 1) {
#pragma unroll
            for (int j = k & (pp - 1); j + k < 16; j += 2 * k) {
#pragma unroll
                for (int i = 0; i < k; ++i) {
                    if ((i + j) / (2 * pp) == (i + j + k) / (2 * pp))
                        cswapT(v[i + j], v[i + j + k]);
                }
            }
        }
    }
}

// ---------------------------------------------------------------------------
// k_all R26: R24 ordering + paired h-write ONLY (single-variable isolation).
// R25 post-mortem: bundling {early x pre-issue, paired h-write} regressed
// 31.2 -> 32.2. Suspect = pre-issue (vmcnt is IN-ORDER: blob-build's L2-hot
// weight-load consumers had to drain the older ~900cyc scattered x gathers
// first -- the R15 hazard in mild form). The paired h-write (-32 LDS write
// instrs) is kept; R25's pass proves its correctness.
//  * h-write: tiles 2z/2z+1 hit the SAME site (mm = m, m+16). Hold even
//    tile's 4 f32 sums in regs; at the odd tile pack cvt_pkrtz(s_e, s_o) ->
//    relu -> 4 ds_write_b32 per tile-PAIR. sH = u32 [site][p*20][m], value
//    f16x2(read m, read m+16); median halver identity holds for any
//    partition into two sorted 16-subsets, so (k, k+16) pairing is valid.
//  * x tiles 0/1 issued AFTER barB (R24 ordering -- do NOT front-run the
//    blob build's weight loads with scattered gathers).
// Kept from R20-R24: f16 MFMA everywhere, direct-global blob build, packed
// relu/sort, fdot2 stats, transposed 20-tile head staging, 5 barriers.
//
// LDS overlay (35840 B, 4 blocks/CU):
//   [0,20480)      phase B: sH  32 x (8 x 20 u32) = 640B/site
//                  phase D: head frag tiles, 20 x 1KB  [after bar4]
//   [20480,35840)  phase A: MLP frag blob, 15 tiles x 1KB (pulled at barB)
//                  phase C: sAgg (5632) @20480 | sB3 @26112 | sW4 @26752 |
//                           sPart @27392   (overlays dead blob tiles)
// ---------------------------------------------------------------------------
#define FB_OFF     20480
#define AGG_OFF    20480
#define B3_OFF     26112
#define W4_OFF     26752
#define PART_OFF   27392
#define SMEM_TOTAL 35840

__global__ __launch_bounds__(256, 4) void k_all(
    const float* __restrict__ x, const int* __restrict__ kmer,
    const int* __restrict__ indices, const float* __restrict__ emb,
    const float* __restrict__ W1, const float* __restrict__ b1,
    const float* __restrict__ W2, const float* __restrict__ b2,
    const float* __restrict__ W3, const float* __restrict__ b3,
    const float* __restrict__ W4, const float* __restrict__ b4,
    float* __restrict__ out, int Gtot)
{
    __shared__ __align__(16) char smem[SMEM_TOTAL];

    const int tid  = threadIdx.x;
    const int lane = tid & 63;
    const int wv   = tid >> 6;
    const int m    = lane & 15;
    const int q    = lane >> 4;

    const int gblk  = blockIdx.x * 32;           // first site of this block
    const int rbase = gblk * 32;                 // first flat read-slot

    // ---- read indices + emb chain (4 groups of 64 reads per wave) ----
    int          rg[4];
    unsigned int egp[4];                         // packed f16 (ex,ey)
    {
        const int lim = Gtot * 32 - 1;
#pragma unroll
        for (int g = 0; g < 4; ++g) {
            int fl = rbase + wv * 256 + g * 64 + lane;
            rg[g] = indices[fl > lim ? lim : fl];
        }
        int kk[4];
#pragma unroll
        for (int g = 0; g < 4; ++g) kk[g] = kmer[rg[g]];
        const float2* emb2 = (const float2*)emb;
#pragma unroll
        for (int g = 0; g < 4; ++g) {
            float2 e = emb2[kk[g]];
            egp[g] = pk16(e.x, e.y);
        }
    }

    // ---- phase A: build f16 fragment blob in LDS, weights read straight
    //      from global (L2-resident) ----
    uint4* fb4w = (uint4*)(smem + FB_OFF);
    {
        const int c  = tid >> 6;                 // tile chunk 0..3
        const int tn = (c < 3) ? 4 : 3;          // tiles 0..14
        for (int tt = 0; tt < tn; ++tt) {
            const int tile = c * 4 + tt;
            unsigned int w[4];
#pragma unroll
            for (int dw = 0; dw < 4; ++dw) {
                const int d = tile * 4 + dw;
                float v0 = 0.f, v1 = 0.f;
                if (d < 40) {
                    int n = d >> 2, j0 = (d & 3) * 2;
                    // permuted hidden rows for the register relay:
                    //   tile 2kt   row(4q+r) = hidden 32kt+8q+r
                    //   tile 2kt+1 row(4q+r) = hidden 32kt+8q+4+r
                    int hid = 32 * (n >> 1) + 8 * (m >> 2) + 4 * (n & 1) + (m & 3);
                    if (hid < HDIM) {
                        int k0 = q * 8 + j0, k1 = k0 + 1;
                        v0 = (k0 < 18) ? W1[k0 * HDIM + hid] : (k0 == 18 ? b1[hid] : 0.f);
                        v1 = (k1 < 18) ? W1[k1 * HDIM + hid] : (k1 == 18 ? b1[hid] : 0.f);
                    }
                } else {
                    int kt = (d - 40) >> 2, j0 = ((d - 40) & 3) * 2;
                    int k0 = kt * 32 + q * 8 + j0, k1 = k0 + 1;
                    if (m < 8) {
                        v0 = (k0 < HDIM) ? W2[k0 * 8 + m]
                                         : (k0 == HDIM ? b2[m] : 0.f);   // b2 row
                        v1 = (k1 < HDIM) ? W2[k1 * 8 + m]
                                         : (k1 == HDIM ? b2[m] : 0.f);
                    }
                }
                w[dw] = pk16(v0, v1);
            }
            fb4w[tile * 64 + lane] = make_uint4(w[0], w[1], w[2], w[3]);
        }
    }
    __syncthreads();                             // barA (blob built)

    // ---- ALL 15 fragment tiles pulled into registers (read LDS once) ----
    uint4 B16[15];
    const uint4* fb4 = (const uint4*)fb4w;
#pragma unroll
    for (int i = 0; i < 15; ++i) B16[i] = fb4[i * 64 + lane];
    const f16x8* frv = (const f16x8*)B16;        // frv[0..9]=L1, frv[10..14]=L2
    __syncthreads();                             // barB: blob region reusable

    const char* xg = (const char*)x;

    // ---- 2-tile-deep register pipeline for the x gather (after barB) ----
    f32x4 xa[2][2];
    auto issueTile = [&](int t) {
        int rr = __shfl(rg[t >> 2], ((t & 3) << 4) + m);
        if (q < 2) {
            const f32x4* src = (const f32x4*)(xg + (size_t)rr * 64 + (size_t)q * 32);
            xa[t & 1][0] = src[0];
            xa[t & 1][1] = src[1];
        }
    };
    issueTile(0);
    issueTile(1);

    unsigned int* sH32 = (unsigned int*)smem;    // [site][p*20][m] f16x2 words
    const f32x4 zero = {0.f, 0.f, 0.f, 0.f};
    const f16x2 z2 = {};

    float se0 = 0.f, se1 = 0.f, se2 = 0.f, se3 = 0.f;   // even-tile sums

#pragma unroll
    for (int t = 0; t < 16; ++t) {
        unsigned int ew = __shfl((int)egp[t >> 2], ((t & 3) << 4) + m);

        // input B-fragment: B[k = q*8+j][n = read m]
        f16x8 bin;
#pragma unroll
        for (int j = 0; j < 8; ++j) bin[j] = (__fp16)0.f;
        if (q < 2) {
            f32x4 u0 = xa[t & 1][0];
            f32x4 u1 = xa[t & 1][1];
            f16x2 p0 = __builtin_amdgcn_cvt_pkrtz(u0[0], u0[1]);
            f16x2 p1 = __builtin_amdgcn_cvt_pkrtz(u0[2], u0[3]);
            f16x2 p2 = __builtin_amdgcn_cvt_pkrtz(u1[0], u1[1]);
            f16x2 p3 = __builtin_amdgcn_cvt_pkrtz(u1[2], u1[3]);
            bin[0] = p0[0]; bin[1] = p0[1]; bin[2] = p1[0]; bin[3] = p1[1];
            bin[4] = p2[0]; bin[5] = p2[1]; bin[6] = p3[0]; bin[7] = p3[1];
        } else if (q == 2) {
            f16x2 ep; __builtin_memcpy(&ep, &ew, 4);
            bin[0] = ep[0]; bin[1] = ep[1];
            bin[2] = (__fp16)1.0f;   // bias-1 input at k==18
        }

        // refill this ring slot with tile t+2 (loads overlap the MFMAs)
        if (t < 14) issueTile(t + 2);

        // layer1 (reg frags) -> packed relu -> layer2 (reg frags)
        f32x4 c2a = zero, c2b = zero;
#pragma unroll
        for (int kt = 0; kt < 5; ++kt) {
            f32x4 ca = __builtin_amdgcn_mfma_f32_16x16x32_f16(frv[2 * kt],     bin, zero, 0, 0, 0);
            f32x4 cb = __builtin_amdgcn_mfma_f32_16x16x32_f16(frv[2 * kt + 1], bin, zero, 0, 0, 0);
            f16x2 h01 = __builtin_elementwise_max(__builtin_amdgcn_cvt_pkrtz(ca[0], ca[1]), z2);
            f16x2 h23 = __builtin_elementwise_max(__builtin_amdgcn_cvt_pkrtz(ca[2], ca[3]), z2);
            f16x2 h45 = __builtin_elementwise_max(__builtin_amdgcn_cvt_pkrtz(cb[0], cb[1]), z2);
            f16x2 h67 = __builtin_elementwise_max(__builtin_amdgcn_cvt_pkrtz(cb[2], cb[3]), z2);
            f16x8 bh;
            bh[0] = h01[0]; bh[1] = h01[1]; bh[2] = h23[0]; bh[3] = h23[1];
            bh[4] = h45[0]; bh[5] = h45[1]; bh[6] = h67[0]; bh[7] = h67[1];
            if (kt == 4 && q == 2) bh[6] = (__fp16)1.0f;   // bias row k==150
            if (kt & 1) c2b = __builtin_amdgcn_mfma_f32_16x16x32_f16(frv[10 + kt], bh, c2b, 0, 0, 0);
            else        c2a = __builtin_amdgcn_mfma_f32_16x16x32_f16(frv[10 + kt], bh, c2a, 0, 0, 0);
        }

        // h: even tile -> hold sums in regs; odd tile -> pack (even,odd)
        // per p and write 4 x ds_write_b32 (tiles 2z/2z+1 share a site)
        if (q < 2) {
            float s0 = c2a[0] + c2b[0], s1 = c2a[1] + c2b[1];
            float s2 = c2a[2] + c2b[2], s3 = c2a[3] + c2b[3];
            if (!(t & 1)) {
                se0 = s0; se1 = s1; se2 = s2; se3 = s3;
            } else {
                int site = wv * 8 + (t >> 1);
                f16x2 w0 = __builtin_elementwise_max(__builtin_amdgcn_cvt_pkrtz(se0, s0), z2);
                f16x2 w1 = __builtin_elementwise_max(__builtin_amdgcn_cvt_pkrtz(se1, s1), z2);
                f16x2 w2 = __builtin_elementwise_max(__builtin_amdgcn_cvt_pkrtz(se2, s2), z2);
                f16x2 w3 = __builtin_elementwise_max(__builtin_amdgcn_cvt_pkrtz(se3, s3), z2);
                unsigned int u0, u1, u2, u3;
                __builtin_memcpy(&u0, &w0, 4);
                __builtin_memcpy(&u1, &w1, 4);
                __builtin_memcpy(&u2, &w2, 4);
                __builtin_memcpy(&u3, &w3, 4);
                unsigned int* hb = sH32 + site * 160 + m;
                hb[(q * 4 + 0) * 20] = u0;
                hb[(q * 4 + 1) * 20] = u1;
                hb[(q * 4 + 2) * 20] = u2;
                hb[(q * 4 + 3) * 20] = u3;
            }
        }
    }
    // NO barrier: agg reads only this wave's own sites (same-wave RAW via
    // lgkmcnt); sAgg region was freed at barB.

    float* sAgg = (float*)(smem + AGG_OFF);
    float* sPart= (float*)(smem + PART_OFF);

    // ---- T14 async-stage, TRANSPOSED, ALL 20 TILES: thread t owns head-frag
    //      dword (tile j=0..19, lane t>>2, dw t&3); load its W3 pair now
    //      (L2-hot; agg hides latency), pack immediately (20 dwords).
    const int fl_ = tid >> 2, fdw = tid & 3;     // frag (lane, dword) owned
    const int fm = fl_ & 15, fq = fl_ >> 4;
    unsigned int hw[20];
#pragma unroll
    for (int j = 0; j < 20; ++j) {
        int jt = j >> 1, kc = j & 1;
        int row = jt * 16 + fm;
        int k0  = kc * 32 + fq * 8 + fdw * 2;
        float v0 = (k0     < 40 && row < HDIM) ? W3[k0 * HDIM + row]       : 0.f;
        float v1 = (k0 + 1 < 40 && row < HDIM) ? W3[(k0 + 1) * HDIM + row] : 0.f;
        hw[j] = pk16(v0, v1);
    }
    float b3r = 0.f, w4r = 0.f;
    if (tid < 160) {
        b3r = (tid < HDIM) ? b3[tid] : 0.f;
        w4r = (tid < HDIM) ? W4[tid] : 0.f;
    }

    // ---- aggregation: packed f16 stats + packed sort + halver merge ----
    // v[k] = (read k, read k+16): a valid partition for the median identity
    const int sg = tid >> 3, p = tid & 7;
    {
        const uint4* hp4 = (const uint4*)(sH32 + sg * 160 + p * 20);
        uint4 rr4[4];
#pragma unroll
        for (int c = 0; c < 4; ++c) rr4[c] = hp4[c];
        f16x2 v[16];
        __builtin_memcpy(v, rr4, 64);

        // sum / sumsq via v_dot2_f32_f16 (exact f16 mul, f32 accumulate)
        float sum = 0.f, sumsq = 0.f;
        const f16x2 ones = {(__fp16)1.0f, (__fp16)1.0f};
#pragma unroll
        for (int k = 0; k < 16; ++k) {
            sum   = __builtin_amdgcn_fdot2(v[k], ones, sum, false);
            sumsq = __builtin_amdgcn_fdot2(v[k], v[k], sumsq, false);
        }

        // packed sort: lows = sorted reads 0..15, highs = sorted reads 16..31
        sort16t(v);

        float mn = fminf((float)v[0][0],  (float)v[0][1]);
        float mx = fmaxf((float)v[15][0], (float)v[15][1]);

        // lower median of 32 = max_i min(a[i], b[15-i]); highs mirror lows
        f16x2 medv = __builtin_elementwise_min(v[0], swap_halves(v[15]));
#pragma unroll
        for (int i = 1; i < 16; ++i)
            medv = __builtin_elementwise_max(
                medv, __builtin_elementwise_min(v[i], swap_halves(v[15 - i])));
        float med = (float)medv[0];

        float mean = sum * (1.f / 32.f);
        float var  = fmaxf((sumsq - 32.f * mean * mean) * (1.f / 31.f), 0.f);
        sAgg[sg * 44 + 0 * 8 + p] = mean;
        sAgg[sg * 44 + 1 * 8 + p] = var;
        sAgg[sg * 44 + 2 * 8 + p] = mn;
        sAgg[sg * 44 + 3 * 8 + p] = med;
        sAgg[sg * 44 + 4 * 8 + p] = mx;
    }
    __syncthreads();   // bar4: all agg done; sH dead -> head frag tiles there

    // ---- phase D: write head fragment tiles (f16) + b3/W4 ----
    unsigned int* hfT = (unsigned int*)smem;     // 20 tiles x 256 dwords
#pragma unroll
    for (int j = 0; j < 20; ++j)
        hfT[j * 256 + tid] = hw[j];
    float* sB3 = (float*)(smem + B3_OFF);
    float* sW4 = (float*)(smem + W4_OFF);
    if (tid < 160) { sB3[tid] = b3r; sW4[tid] = w4r; }
    __syncthreads();   // bar5

    // ---- lanes pull their 10 head-fragment uint4s ----
    const int jthalf = wv >> 1, sh = wv & 1;
    uint4 HF[10];
    {
        const uint4* hfv = (const uint4*)hfT;
#pragma unroll
        for (int i = 0; i < 10; ++i) {
            int jt = jthalf * 5 + (i >> 1), kc = i & 1;
            HF[i] = hfv[(jt * 2 + kc) * 64 + lane];
        }
    }
    const f16x8* hf = (const f16x8*)HF;

    // ---- head MLP via f16 MFMA: Z[j][site] = W3^T @ AGG, wave=(jthalf,sh) --
    // B-frag: lane(m,q) holds AGG[k = kc*32+q*8+j][site sh*16+m], split hi/lo
    const int site = sh * 16 + m;
    const float* ar = sAgg + site * 44;
    f16x8 bh0, bl0, bh1, bl1;
    {
        float4 a0 = *(const float4*)(ar + q * 8);
        float4 a1 = *(const float4*)(ar + q * 8 + 4);
        float va[8] = {a0.x, a0.y, a0.z, a0.w, a1.x, a1.y, a1.z, a1.w};
#pragma unroll
        for (int j = 0; j < 8; ++j) {
            __fp16 hi = (__fp16)va[j];
            bh0[j] = hi;
            bl0[j] = (__fp16)(va[j] - (float)hi);
        }
    }
    if (q == 0) {       // kc=1 covers k = 32..39 (stat 4); other q are zero
        float4 a0 = *(const float4*)(ar + 32);
        float4 a1 = *(const float4*)(ar + 36);
        float va[8] = {a0.x, a0.y, a0.z, a0.w, a1.x, a1.y, a1.z, a1.w};
#pragma unroll
        for (int j = 0; j < 8; ++j) {
            __fp16 hi = (__fp16)va[j];
            bh1[j] = hi;
            bl1[j] = (__fp16)(va[j] - (float)hi);
        }
    } else {
#pragma unroll
        for (int j = 0; j < 8; ++j) { bh1[j] = (__fp16)0.f; bl1[j] = (__fp16)0.f; }
    }

    const float4* b3v = (const float4*)sB3;
    const float4* w4v = (const float4*)sW4;
    float sacc = 0.f;
#pragma unroll
    for (int jj = 0; jj < 5; ++jj) {
        int jt = jthalf * 5 + jj;
        float4 bi = b3v[jt * 4 + q];             // rows jt*16+q*4 .. +3
        f32x4 acc = {bi.x, bi.y, bi.z, bi.w};
        acc = __builtin_amdgcn_mfma_f32_16x16x32_f16(hf[jj * 2 + 0], bh0, acc, 0, 0, 0);
        acc = __builtin_amdgcn_mfma_f32_16x16x32_f16(hf[jj * 2 + 0], bl0, acc, 0, 0, 0);
        acc = __builtin_amdgcn_mfma_f32_16x16x32_f16(hf[jj * 2 + 1], bh1, acc, 0, 0, 0);
        acc = __builtin_amdgcn_mfma_f32_16x16x32_f16(hf[jj * 2 + 1], bl1, acc, 0, 0, 0);
        float4 w4q = w4v[jt * 4 + q];
        sacc = fmaf(fmaxf(acc[0], 0.f), w4q.x, sacc);
        sacc = fmaf(fmaxf(acc[1], 0.f), w4q.y, sacc);
        sacc = fmaf(fmaxf(acc[2], 0.f), w4q.z, sacc);
        sacc = fmaf(fmaxf(acc[3], 0.f), w4q.w, sacc);
    }
    // reduce over the 4 q row-groups (j within tile), then across jthalf waves
    sacc += __shfl_xor(sacc, 16);
    sacc += __shfl_xor(sacc, 32);
    if (jthalf == 1 && lane < 16) sPart[sh * 16 + lane] = sacc;
    __syncthreads();   // bar6
    if (jthalf == 0 && lane < 16) {
        int s2 = sh * 16 + lane;
        float zf = sacc + sPart[s2] + b4[0];
        if (gblk + s2 < Gtot) out[gblk + s2] = 1.f / (1.f + expf(-zf));
    }
}

// ---------------------------------------------------------------------------
extern "C" void kernel_launch(void* const* d_in, const int* in_sizes, int n_in,
                              void* d_out, int out_size, void* d_ws, size_t ws_size,
                              hipStream_t stream) {
    const float* x       = (const float*)d_in[0];
    const int*   kmer    = (const int*)  d_in[1];
    const int*   indices = (const int*)  d_in[2];
    const float* emb     = (const float*)d_in[3];
    const float* W1      = (const float*)d_in[4];
    const float* b1      = (const float*)d_in[5];
    const float* W2      = (const float*)d_in[6];
    const float* b2      = (const float*)d_in[7];
    const float* W3      = (const float*)d_in[8];
    const float* b3      = (const float*)d_in[9];
    const float* W4      = (const float*)d_in[10];
    const float* b4      = (const float*)d_in[11];

    float* out = (float*)d_out;
    const int G = out_size;

    const int grid = (G + 31) / 32;              // 32 sites / block
    k_all<<<grid, 256, 0, stream>>>(x, kmer, indices, emb,
                                    W1, b1, W2, b2, W3, b3, W4, b4,
                                    out, G);
}

// Round 19
// 31.385 us; speedup vs baseline: 1.0258x; 1.0146x over previous
//
#include <hip/hip_runtime.h>
#include <hip/hip_bf16.h>
#include <hip/hip_fp16.h>
#include <math.h>

#define HDIM 150

typedef __fp16   f16x8  __attribute__((ext_vector_type(8)));   // matches builtin 'h'
typedef __fp16   f16x2  __attribute__((ext_vector_type(2)));
typedef float    f32x4  __attribute__((ext_vector_type(4)));

__device__ __forceinline__ unsigned int pk16(float a, float b) {
    f16x2 p = __builtin_amdgcn_cvt_pkrtz(a, b);
    unsigned int w; __builtin_memcpy(&w, &p, 4);
    return w;
}

__device__ __forceinline__ f16x2 swap_halves(f16x2 v) {
    unsigned int u; __builtin_memcpy(&u, &v, 4);
    u = __builtin_amdgcn_alignbit(u, u, 16);
    f16x2 r; __builtin_memcpy(&r, &u, 4);
    return r;
}

// ---------------------------------------------------------------------------
// fully unrolled Batcher odd-even mergesort, n = 16 (f16x2: lows and highs
// sorted INDEPENDENTLY via v_pk_min/max_f16)
// ---------------------------------------------------------------------------
template <typename T>
__device__ __forceinline__ void cswapT(T& a, T& b) {
    T lo = __builtin_elementwise_min(a, b);
    T hi = __builtin_elementwise_max(a, b);
    a = lo; b = hi;
}

template <typename T>
__device__ __forceinline__ void sort16t(T v[16]) {
#pragma unroll
    for (int pp = 1; pp < 16; pp <<= 1) {
#pragma unroll
        for (int k = pp; k >= 1; k >>= 1) {
#pragma unroll
            for (int j = k & (pp - 1); j + k < 16; j += 2 * k) {
#pragma unroll
                for (int i = 0; i < k; ++i) {
                    if ((i + j) / (2 * pp) == (i + j + k) / (2 * pp))
                        cswapT(v[i + j], v[i + j + k]);
                }
            }
        }
    }
}

// ---------------------------------------------------------------------------
// k_all R27 == R24 exact revert (best measured: 31.2us).
// R25 (early x pre-issue + paired h-write) regressed to 32.2; R26 (paired
// h-write alone) measured 31.8 -- both halves non-improvements. R24 is the
// session optimum; locking it in.
// Structure: single kernel, 32 sites/block, grid 1024, 256 thr, 4 blk/CU.
//  * f16 MFMA relay (L1 tile-pair -> packed relu -> L2) with all fragments
//    register-resident (15 uint4, built per-block in LDS from global-read
//    weights -- no sWgt staging pass).
//  * x gathered direct to VGPRs, 2-deep ring, issued AFTER barB (vmcnt is
//    in-order: scattered gathers must not front-run L2-hot weight loads).
//  * h -> LDS [site][p stride-40 f16][mm]; agg = 4x ds_read_b128 + fdot2
//    stats + packed f16x2 sort16 + bitonic-halver lower-median-of-32.
//  * head: transposed T14 staging -- thread t owns its fragment dword in
//    all 20 tiles, loads 40 W3 values before agg (latency hidden), packs
//    to 20 dwords, ds_write_b32 after bar4; head MFMA in f16 hi/lo split.
//
// LDS overlay (35840 B, 4 blocks/CU):
//   [0,20480)      phase B: sH  32 x (8 x 40) f16 = 640B/site
//                  phase D: head frag tiles, 20 x 1KB  [after bar4]
//   [20480,35840)  phase A: MLP frag blob, 15 tiles x 1KB (pulled at barB)
//                  phase C: sAgg (5632) @20480 | sB3 @26112 | sW4 @26752 |
//                           sPart @27392   (overlays dead blob tiles)
// Barriers: barA (blob built) -> pull -> barB (blob dead) -> MLP ->
// [none] -> agg -> bar4 (sH dead) -> frag/b3/W4 writes -> bar5 -> head ->
// bar6 -> out.
// ---------------------------------------------------------------------------
#define FB_OFF     20480
#define AGG_OFF    20480
#define B3_OFF     26112
#define W4_OFF     26752
#define PART_OFF   27392
#define SMEM_TOTAL 35840

__global__ __launch_bounds__(256, 4) void k_all(
    const float* __restrict__ x, const int* __restrict__ kmer,
    const int* __restrict__ indices, const float* __restrict__ emb,
    const float* __restrict__ W1, const float* __restrict__ b1,
    const float* __restrict__ W2, const float* __restrict__ b2,
    const float* __restrict__ W3, const float* __restrict__ b3,
    const float* __restrict__ W4, const float* __restrict__ b4,
    float* __restrict__ out, int Gtot)
{
    __shared__ __align__(16) char smem[SMEM_TOTAL];

    const int tid  = threadIdx.x;
    const int lane = tid & 63;
    const int wv   = tid >> 6;
    const int m    = lane & 15;
    const int q    = lane >> 4;

    const int gblk  = blockIdx.x * 32;           // first site of this block
    const int rbase = gblk * 32;                 // first flat read-slot

    // ---- read indices + emb chain (4 groups of 64 reads per wave) ----
    int          rg[4];
    unsigned int egp[4];                         // packed f16 (ex,ey)
    {
        const int lim = Gtot * 32 - 1;
#pragma unroll
        for (int g = 0; g < 4; ++g) {
            int fl = rbase + wv * 256 + g * 64 + lane;
            rg[g] = indices[fl > lim ? lim : fl];
        }
        int kk[4];
#pragma unroll
        for (int g = 0; g < 4; ++g) kk[g] = kmer[rg[g]];
        const float2* emb2 = (const float2*)emb;
#pragma unroll
        for (int g = 0; g < 4; ++g) {
            float2 e = emb2[kk[g]];
            egp[g] = pk16(e.x, e.y);
        }
    }

    // ---- phase A: build f16 fragment blob in LDS, weights read straight
    //      from global (L2-resident; staging through LDS was pure overhead)
    uint4* fb4w = (uint4*)(smem + FB_OFF);
    {
        const int c  = tid >> 6;                 // tile chunk 0..3
        const int tn = (c < 3) ? 4 : 3;          // tiles 0..14
        for (int tt = 0; tt < tn; ++tt) {
            const int tile = c * 4 + tt;
            unsigned int w[4];
#pragma unroll
            for (int dw = 0; dw < 4; ++dw) {
                const int d = tile * 4 + dw;
                float v0 = 0.f, v1 = 0.f;
                if (d < 40) {
                    int n = d >> 2, j0 = (d & 3) * 2;
                    // permuted hidden rows for the register relay:
                    //   tile 2kt   row(4q+r) = hidden 32kt+8q+r
                    //   tile 2kt+1 row(4q+r) = hidden 32kt+8q+4+r
                    int hid = 32 * (n >> 1) + 8 * (m >> 2) + 4 * (n & 1) + (m & 3);
                    if (hid < HDIM) {
                        int k0 = q * 8 + j0, k1 = k0 + 1;
                        v0 = (k0 < 18) ? W1[k0 * HDIM + hid] : (k0 == 18 ? b1[hid] : 0.f);
                        v1 = (k1 < 18) ? W1[k1 * HDIM + hid] : (k1 == 18 ? b1[hid] : 0.f);
                    }
                } else {
                    int kt = (d - 40) >> 2, j0 = ((d - 40) & 3) * 2;
                    int k0 = kt * 32 + q * 8 + j0, k1 = k0 + 1;
                    if (m < 8) {
                        v0 = (k0 < HDIM) ? W2[k0 * 8 + m]
                                         : (k0 == HDIM ? b2[m] : 0.f);   // b2 row
                        v1 = (k1 < HDIM) ? W2[k1 * 8 + m]
                                         : (k1 == HDIM ? b2[m] : 0.f);
                    }
                }
                w[dw] = pk16(v0, v1);
            }
            fb4w[tile * 64 + lane] = make_uint4(w[0], w[1], w[2], w[3]);
        }
    }
    __syncthreads();                             // barA (blob built)

    // ---- ALL 15 fragment tiles pulled into registers (read LDS once) ----
    uint4 B16[15];
    const uint4* fb4 = (const uint4*)fb4w;
#pragma unroll
    for (int i = 0; i < 15; ++i) B16[i] = fb4[i * 64 + lane];
    const f16x8* frv = (const f16x8*)B16;        // frv[0..9]=L1, frv[10..14]=L2
    __syncthreads();                             // barB: blob region reusable

    const char* xg = (const char*)x;

    // ---- 2-tile-deep register pipeline for the x gather ----
    f32x4 xa[2][2];
    auto issueTile = [&](int t) {
        int rr = __shfl(rg[t >> 2], ((t & 3) << 4) + m);
        if (q < 2) {
            const f32x4* src = (const f32x4*)(xg + (size_t)rr * 64 + (size_t)q * 32);
            xa[t & 1][0] = src[0];
            xa[t & 1][1] = src[1];
        }
    };
    issueTile(0);
    issueTile(1);

    __fp16* sH = (__fp16*)smem;
    const f32x4 zero = {0.f, 0.f, 0.f, 0.f};
    const f16x2 z2 = {};

#pragma unroll
    for (int t = 0; t < 16; ++t) {
        unsigned int ew = __shfl((int)egp[t >> 2], ((t & 3) << 4) + m);

        // input B-fragment: B[k = q*8+j][n = read m]
        f16x8 bin;
#pragma unroll
        for (int j = 0; j < 8; ++j) bin[j] = (__fp16)0.f;
        if (q < 2) {
            f32x4 u0 = xa[t & 1][0];
            f32x4 u1 = xa[t & 1][1];
            f16x2 p0 = __builtin_amdgcn_cvt_pkrtz(u0[0], u0[1]);
            f16x2 p1 = __builtin_amdgcn_cvt_pkrtz(u0[2], u0[3]);
            f16x2 p2 = __builtin_amdgcn_cvt_pkrtz(u1[0], u1[1]);
            f16x2 p3 = __builtin_amdgcn_cvt_pkrtz(u1[2], u1[3]);
            bin[0] = p0[0]; bin[1] = p0[1]; bin[2] = p1[0]; bin[3] = p1[1];
            bin[4] = p2[0]; bin[5] = p2[1]; bin[6] = p3[0]; bin[7] = p3[1];
        } else if (q == 2) {
            f16x2 ep; __builtin_memcpy(&ep, &ew, 4);
            bin[0] = ep[0]; bin[1] = ep[1];
            bin[2] = (__fp16)1.0f;   // bias-1 input at k==18
        }

        // refill this ring slot with tile t+2 (loads overlap the MFMAs)
        if (t < 14) issueTile(t + 2);

        // layer1 (reg frags) -> packed relu -> layer2 (reg frags)
        f32x4 c2a = zero, c2b = zero;
#pragma unroll
        for (int kt = 0; kt < 5; ++kt) {
            f32x4 ca = __builtin_amdgcn_mfma_f32_16x16x32_f16(frv[2 * kt],     bin, zero, 0, 0, 0);
            f32x4 cb = __builtin_amdgcn_mfma_f32_16x16x32_f16(frv[2 * kt + 1], bin, zero, 0, 0, 0);
            f16x2 h01 = __builtin_elementwise_max(__builtin_amdgcn_cvt_pkrtz(ca[0], ca[1]), z2);
            f16x2 h23 = __builtin_elementwise_max(__builtin_amdgcn_cvt_pkrtz(ca[2], ca[3]), z2);
            f16x2 h45 = __builtin_elementwise_max(__builtin_amdgcn_cvt_pkrtz(cb[0], cb[1]), z2);
            f16x2 h67 = __builtin_elementwise_max(__builtin_amdgcn_cvt_pkrtz(cb[2], cb[3]), z2);
            f16x8 bh;
            bh[0] = h01[0]; bh[1] = h01[1]; bh[2] = h23[0]; bh[3] = h23[1];
            bh[4] = h45[0]; bh[5] = h45[1]; bh[6] = h67[0]; bh[7] = h67[1];
            if (kt == 4 && q == 2) bh[6] = (__fp16)1.0f;   // bias row k==150
            if (kt & 1) c2b = __builtin_amdgcn_mfma_f32_16x16x32_f16(frv[10 + kt], bh, c2b, 0, 0, 0);
            else        c2a = __builtin_amdgcn_mfma_f32_16x16x32_f16(frv[10 + kt], bh, c2a, 0, 0, 0);
        }

        // h -> LDS transposed layout [site][p (stride 40)][mm]
        if (q < 2) {
            int br   = wv * 256 + t * 16 + m;    // block read idx
            int site = br >> 5, mm = br & 31;
            float s0 = c2a[0] + c2b[0], s1 = c2a[1] + c2b[1];
            float s2 = c2a[2] + c2b[2], s3 = c2a[3] + c2b[3];
            f16x2 o01 = __builtin_elementwise_max(__builtin_amdgcn_cvt_pkrtz(s0, s1), z2);
            f16x2 o23 = __builtin_elementwise_max(__builtin_amdgcn_cvt_pkrtz(s2, s3), z2);
            __fp16* hb = sH + site * 320 + mm;
            hb[(q * 4 + 0) * 40] = o01[0];
            hb[(q * 4 + 1) * 40] = o01[1];
            hb[(q * 4 + 2) * 40] = o23[0];
            hb[(q * 4 + 3) * 40] = o23[1];
        }
    }
    // NO barrier: agg reads only this wave's own sites (same-wave RAW via
    // lgkmcnt); sAgg region was freed at barB.

    float* sAgg = (float*)(smem + AGG_OFF);
    float* sPart= (float*)(smem + PART_OFF);

    // ---- T14 async-stage, TRANSPOSED, ALL 20 TILES: thread t owns head-frag
    //      dword (tile j=0..19, lane t>>2, dw t&3); load its W3 pair now
    //      (L2-hot; agg hides latency), pack immediately (20 dwords, not 40
    //      floats), write to LDS after bar4.
    const int fl_ = tid >> 2, fdw = tid & 3;     // frag (lane, dword) owned
    const int fm = fl_ & 15, fq = fl_ >> 4;
    unsigned int hw[20];
#pragma unroll
    for (int j = 0; j < 20; ++j) {
        int jt = j >> 1, kc = j & 1;
        int row = jt * 16 + fm;
        int k0  = kc * 32 + fq * 8 + fdw * 2;
        float v0 = (k0     < 40 && row < HDIM) ? W3[k0 * HDIM + row]       : 0.f;
        float v1 = (k0 + 1 < 40 && row < HDIM) ? W3[(k0 + 1) * HDIM + row] : 0.f;
        hw[j] = pk16(v0, v1);
    }
    float b3r = 0.f, w4r = 0.f;
    if (tid < 160) {
        b3r = (tid < HDIM) ? b3[tid] : 0.f;
        w4r = (tid < HDIM) ? W4[tid] : 0.f;
    }

    // ---- aggregation: packed f16 stats + packed sort + halver merge ----
    const int sg = tid >> 3, p = tid & 7;
    {
        const __fp16* hp = sH + sg * 320 + p * 40;
        uint4 rr4[4];
#pragma unroll
        for (int c = 0; c < 4; ++c) rr4[c] = *(const uint4*)(hp + c * 8);
        f16x2 v[16];                             // v[k] = (read 2k, read 2k+1)
        __builtin_memcpy(v, rr4, 64);

        // sum / sumsq via v_dot2_f32_f16 (exact f16 mul, f32 accumulate)
        float sum = 0.f, sumsq = 0.f;
        const f16x2 ones = {(__fp16)1.0f, (__fp16)1.0f};
#pragma unroll
        for (int k = 0; k < 16; ++k) {
            sum   = __builtin_amdgcn_fdot2(v[k], ones, sum, false);
            sumsq = __builtin_amdgcn_fdot2(v[k], v[k], sumsq, false);
        }

        // packed sort: lows = sorted even reads, highs = sorted odd reads
        sort16t(v);

        float mn = fminf((float)v[0][0],  (float)v[0][1]);
        float mx = fmaxf((float)v[15][0], (float)v[15][1]);

        // lower median of 32 = max_i min(a[i], b[15-i]); highs mirror lows
        f16x2 medv = __builtin_elementwise_min(v[0], swap_halves(v[15]));
#pragma unroll
        for (int i = 1; i < 16; ++i)
            medv = __builtin_elementwise_max(
                medv, __builtin_elementwise_min(v[i], swap_halves(v[15 - i])));
        float med = (float)medv[0];

        float mean = sum * (1.f / 32.f);
        float var  = fmaxf((sumsq - 32.f * mean * mean) * (1.f / 31.f), 0.f);
        sAgg[sg * 44 + 0 * 8 + p] = mean;
        sAgg[sg * 44 + 1 * 8 + p] = var;
        sAgg[sg * 44 + 2 * 8 + p] = mn;
        sAgg[sg * 44 + 3 * 8 + p] = med;
        sAgg[sg * 44 + 4 * 8 + p] = mx;
    }
    __syncthreads();   // bar4: all agg done; sH dead -> head frag tiles there

    // ---- phase D: write head fragment tiles (f16) + b3/W4 ----
    unsigned int* hfT = (unsigned int*)smem;     // 20 tiles x 256 dwords
#pragma unroll
    for (int j = 0; j < 20; ++j)
        hfT[j * 256 + tid] = hw[j];
    float* sB3 = (float*)(smem + B3_OFF);
    float* sW4 = (float*)(smem + W4_OFF);
    if (tid < 160) { sB3[tid] = b3r; sW4[tid] = w4r; }
    __syncthreads();   // bar5

    // ---- lanes pull their 10 head-fragment uint4s ----
    const int jthalf = wv >> 1, sh = wv & 1;
    uint4 HF[10];
    {
        const uint4* hfv = (const uint4*)hfT;
#pragma unroll
        for (int i = 0; i < 10; ++i) {
            int jt = jthalf * 5 + (i >> 1), kc = i & 1;
            HF[i] = hfv[(jt * 2 + kc) * 64 + lane];
        }
    }
    const f16x8* hf = (const f16x8*)HF;

    // ---- head MLP via f16 MFMA: Z[j][site] = W3^T @ AGG, wave=(jthalf,sh) --
    // B-frag: lane(m,q) holds AGG[k = kc*32+q*8+j][site sh*16+m], split hi/lo
    const int site = sh * 16 + m;
    const float* ar = sAgg + site * 44;
    f16x8 bh0, bl0, bh1, bl1;
    {
        float4 a0 = *(const float4*)(ar + q * 8);
        float4 a1 = *(const float4*)(ar + q * 8 + 4);
        float va[8] = {a0.x, a0.y, a0.z, a0.w, a1.x, a1.y, a1.z, a1.w};
#pragma unroll
        for (int j = 0; j < 8; ++j) {
            __fp16 hi = (__fp16)va[j];
            bh0[j] = hi;
            bl0[j] = (__fp16)(va[j] - (float)hi);
        }
    }
    if (q == 0) {       // kc=1 covers k = 32..39 (stat 4); other q are zero
        float4 a0 = *(const float4*)(ar + 32);
        float4 a1 = *(const float4*)(ar + 36);
        float va[8] = {a0.x, a0.y, a0.z, a0.w, a1.x, a1.y, a1.z, a1.w};
#pragma unroll
        for (int j = 0; j < 8; ++j) {
            __fp16 hi = (__fp16)va[j];
            bh1[j] = hi;
            bl1[j] = (__fp16)(va[j] - (float)hi);
        }
    } else {
#pragma unroll
        for (int j = 0; j < 8; ++j) { bh1[j] = (__fp16)0.f; bl1[j] = (__fp16)0.f; }
    }

    const float4* b3v = (const float4*)sB3;
    const float4* w4v = (const float4*)sW4;
    float sacc = 0.f;
#pragma unroll
    for (int jj = 0; jj < 5; ++jj) {
        int jt = jthalf * 5 + jj;
        float4 bi = b3v[jt * 4 + q];             // rows jt*16+q*4 .. +3
        f32x4 acc = {bi.x, bi.y, bi.z, bi.w};
        acc = __builtin_amdgcn_mfma_f32_16x16x32_f16(hf[jj * 2 + 0], bh0, acc, 0, 0, 0);
        acc = __builtin_amdgcn_mfma_f32_16x16x32_f16(hf[jj * 2 + 0], bl0, acc, 0, 0, 0);
        acc = __builtin_amdgcn_mfma_f32_16x16x32_f16(hf[jj * 2 + 1], bh1, acc, 0, 0, 0);
        acc = __builtin_amdgcn_mfma_f32_16x16x32_f16(hf[jj * 2 + 1], bl1, acc, 0, 0, 0);
        float4 w4q = w4v[jt * 4 + q];
        sacc = fmaf(fmaxf(acc[0], 0.f), w4q.x, sacc);
        sacc = fmaf(fmaxf(acc[1], 0.f), w4q.y, sacc);
        sacc = fmaf(fmaxf(acc[2], 0.f), w4q.z, sacc);
        sacc = fmaf(fmaxf(acc[3], 0.f), w4q.w, sacc);
    }
    // reduce over the 4 q row-groups (j within tile), then across jthalf waves
    sacc += __shfl_xor(sacc, 16);
    sacc += __shfl_xor(sacc, 32);
    if (jthalf == 1 && lane < 16) sPart[sh * 16 + lane] = sacc;
    __syncthreads();   // bar6
    if (jthalf == 0 && lane < 16) {
        int s2 = sh * 16 + lane;
        float zf = sacc + sPart[s2] + b4[0];
        if (gblk + s2 < Gtot) out[gblk + s2] = 1.f / (1.f + expf(-zf));
    }
}

// ---------------------------------------------------------------------------
extern "C" void kernel_launch(void* const* d_in, const int* in_sizes, int n_in,
                              void* d_out, int out_size, void* d_ws, size_t ws_size,
                              hipStream_t stream) {
    const float* x       = (const float*)d_in[0];
    const int*   kmer    = (const int*)  d_in[1];
    const int*   indices = (const int*)  d_in[2];
    const float* emb     = (const float*)d_in[3];
    const float* W1      = (const float*)d_in[4];
    const float* b1      = (const float*)d_in[5];
    const float* W2      = (const float*)d_in[6];
    const float* b2      = (const float*)d_in[7];
    const float* W3      = (const float*)d_in[8];
    const float* b3      = (const float*)d_in[9];
    const float* W4      = (const float*)d_in[10];
    const float* b4      = (const float*)d_in[11];

    float* out = (float*)d_out;
    const int G = out_size;

    const int grid = (G + 31) / 32;              // 32 sites / block
    k_all<<<grid, 256, 0, stream>>>(x, kmer, indices, emb,
                                    W1, b1, W2, b2, W3, b3, W4, b4,
                                    out, G);
}